// Round 3
// baseline (256.153 us; speedup 1.0000x reference)
//
#include <hip/hip_runtime.h>
#include <stdint.h>

typedef __attribute__((ext_vector_type(8))) short bf16x8;
typedef __attribute__((ext_vector_type(4))) float f32x4;
typedef __attribute__((ext_vector_type(4))) unsigned short u16x4;

#define NB 32
#define HH 128
#define WW 128
#define CI 128
#define CO 128
#define HO 126
#define WO 126
#define TH 16
#define TW 16
#define PHh 18
#define PWw 18
#define NROW (PHh * PWw)   // 324 patch rows

__device__ __forceinline__ unsigned short f2bf(float f) {
  union { float f; unsigned u; } x; x.f = f;
  unsigned u = x.u;
  u += 0x7FFFu + ((u >> 16) & 1u);   // RNE round to bf16
  return (unsigned short)(u >> 16);
}

// cvt_pk_bf16_f32: RNE, packs 2 f32 -> 2 bf16 in one VALU op (no builtin on gfx950)
__device__ __forceinline__ unsigned cvtpk_bf16(float a, float b) {
  unsigned r;
  asm("v_cvt_pk_bf16_f32 %0, %1, %2" : "=v"(r) : "v"(a), "v"(b));
  return r;  // low16 = bf16(a), high16 = bf16(b)
}

// XOR-swizzle for 128B (64-short) rows: short-idx ^= ((row&7)<<3), row = idx>>6
// (measured 0 bank conflicts in this geometry)
__device__ __forceinline__ int swz64(int idx) { return idx ^ (((idx >> 6) & 7) << 3); }

// prep: [b,p][ci][co] f32 -> fragment-blocked bf16, slice-major [b][ch][p][kc]:
//   slice = (ch*9+p)*2+kc (4096 shorts each); within: f*512 + lane*8 + e
//   holds kin[b,p][ci = ch*64+kc*32+(lane>>4)*8+e][co = (f>>2)*64+(f&3)*16+(lane&15)]
__global__ void prep_kt(const float* __restrict__ kin, unsigned short* __restrict__ ktr) {
  __shared__ unsigned short t[CI * CO];  // 32 KB
  int bp = blockIdx.x;  // b*9+p, 0..287
  int b = bp / 9, p = bp % 9;
  const float* src = kin + (size_t)bp * (CI * CO);
  unsigned short* dstb = ktr + (size_t)b * (9 * CI * CO);
  for (int i = threadIdx.x; i < CI * CO / 4; i += blockDim.x) {
    f32x4 v = *(const f32x4*)(src + i * 4);
    u16x4 o;
    o.x = f2bf(v.x); o.y = f2bf(v.y); o.z = f2bf(v.z); o.w = f2bf(v.w);
    *(u16x4*)&t[i * 4] = o;
  }
  __syncthreads();
  for (int j = threadIdx.x; j < 2048; j += blockDim.x) {  // j = (sl*8+f)*64+lane
    int lane = j & 63, f = (j >> 6) & 7, sl = j >> 9;     // sl = ch*2+kc
    int ch = sl >> 1, kc = sl & 1;
    int co = (f >> 2) * 64 + (f & 3) * 16 + (lane & 15);
    int ci0 = ch * 64 + kc * 32 + (lane >> 4) * 8;
    bf16x8 v;
#pragma unroll
    for (int e = 0; e < 8; ++e) v[e] = t[(ci0 + e) * CO + co];
    int slice = (ch * 9 + p) * 2 + kc;
    *(bf16x8*)&dstb[(size_t)slice * 4096 + f * 512 + lane * 8] = v;
  }
}

// naive fallback (only if ws_size too small — not expected on this harness)
__global__ void conv_naive(const float* __restrict__ X, const float* __restrict__ Kf,
                           float* __restrict__ out) {
  int idx = blockIdx.x * blockDim.x + threadIdx.x;           // over B*HO*WO*CO
  if (idx >= NB * HO * WO * CO) return;
  int co = idx & 127, t = idx >> 7;
  int wp = t % WO; t /= WO;
  int hp = t % HO; int b = t / HO;
  const float* xb = X + (size_t)b * HH * WW * CI;
  const float* kb = Kf + (size_t)b * 9 * CI * CO;
  float s = 0.f;
  for (int p = 0; p < 9; ++p) {
    int kh = p / 3, kw = p % 3;
    const float* xr = xb + ((size_t)(hp + kh) * WW + (wp + kw)) * CI;
    const float* kr = kb + (size_t)p * CI * CO + co;
    for (int ci = 0; ci < CI; ++ci) s += xr[ci] * kr[(size_t)ci * CO];
  }
  out[idx] = s;
}

__global__ __launch_bounds__(512, 4) void conv_main(
    const float* __restrict__ X, const unsigned short* __restrict__ Kt,
    float* __restrict__ out) {
  // One Cin-half of the 18x18 input patch, swizzled 128B rows.
  __shared__ unsigned short lds_a[NROW * 64];  // 41472 B -> 2 blocks/CU

  const int tid = threadIdx.x;
  const int lane = tid & 63;
  const int wid = tid >> 6;            // 8 waves, 4 (h) x 2 (co)
  const int wr = wid >> 1, wc = wid & 1;

  // XCD-clustered block swizzle: 4 whole batches per XCD keeps the B working
  // set L2-resident (verified: FETCH 200->146MB).
  const int l = blockIdx.x;            // 0..2047
  const int xcd = l & 7, j = l >> 3;   // j: 0..255
  const int b = xcd * 4 + (j >> 6);    // 4 batches per XCD
  const int t = j & 63;                // tile within batch (8x8 of 16x16)
  const int ht = t >> 3, wt = t & 7;
  const int h0 = ht * TH, w0 = wt * TW;
  const int ks = lane >> 4, lr = lane & 15;

  const float* xb = X + (size_t)b * HH * WW * CI;

  // ---- stage precompute: slot s = tid + k*512; row = (tid>>4) + 32k ----
  // ci4 = tid&15 constant; (row+32)&7 == row&7 so the swizzle XOR is constant
  // per thread -> dst = dst0 + k*2048 shorts exactly.
  const int ci4 = tid & 15;
  const int row0 = tid >> 4;                  // 0..31
  const int hi0 = (row0 >= PWw) ? 1 : 0;
  const int wi0 = row0 - hi0 * PWw;
  const int dst0 = swz64(row0 * 64 + ci4 * 4);

  auto stageA = [&](int ch) {
    int h = hi0, w = wi0;
    const float* srcb = xb + ch * 64 + ci4 * 4;
#pragma unroll
    for (int k = 0; k < 11; ++k) {            // 10 full rounds + 4-row tail
      if (k < 10 || tid < 64) {
        int gh = h0 + h, gw = w0 + w;
        bool ok = (gh | gw) < HH;             // gh<128 && gw<128 (both <256)
        const float* src = srcb + ((size_t)(((gh & 127) << 7) + (gw & 127)) << 7);
        f32x4 v = *(const f32x4*)src;
        uint2 o;
        o.x = ok ? cvtpk_bf16(v.x, v.y) : 0u;
        o.y = ok ? cvtpk_bf16(v.z, v.w) : 0u;
        *(uint2*)&lds_a[dst0 + k * 2048] = o; // k*4096B folds into ds offset imm
      }
      w += 14;                                // advance 32 rows: h+=1, w+=14 wrap
      int wrap = (w >= PWw) ? 1 : 0;
      h += 1 + wrap;
      w -= wrap ? PWw : 0;
    }
  };

  // ---- compute precompute: row(m,kh,kw) = RB0 + m*18 + Cs, Cs = kh*18+kw ----
  // byte addr = (row*128 + kc*64 + ks*16) ^ ((row&7)<<4); 18 mod 8 = 2.
  const int RB0 = (wr * 4) * PWw + lr;
  const int ub0 = RB0 * 128 + ks * 16;
  const int rm70 = RB0 & 7;
  const char* ldsb = (const char*)lds_a;

  f32x4 zero = {0.f, 0.f, 0.f, 0.f};
  f32x4 acc[4][4];
#pragma unroll
  for (int m = 0; m < 4; ++m)
#pragma unroll
    for (int n = 0; n < 4; ++n) acc[m][n] = zero;

  // B slices: slice = (ch*9+p)*2+kc; wave loads its 4 co-fragments as 4
  // contiguous 1KB bursts (L2/L1-resident after XCD clustering).
  const unsigned short* ktw = Kt + (size_t)b * 9 * CI * CO + (wc * 4) * 512 + lane * 8;

  bf16x8 Hf[4];
  auto loadBh = [&](int slice) {
#pragma unroll
    for (int n = 0; n < 4; ++n)
      Hf[n] = *(const bf16x8*)&ktw[(size_t)slice * 4096 + n * 512];
  };

#pragma unroll 1
  for (int ch = 0; ch < 2; ++ch) {
    if (ch) __syncthreads();           // all waves done reading previous half
    loadBh(ch * 18);                   // B prefetch flies during staging
    stageA(ch);
    __syncthreads();                   // lds_a ready

    // fully-unrolled 18 half-steps: all kh/kw/kc/Cs compile-time
#pragma unroll
    for (int kh = 0; kh < 3; ++kh) {
#pragma unroll
      for (int jj = 0; jj < 6; ++jj) {
        const int kw = jj >> 1, kc = jj & 1;
        const int s = kh * 6 + jj;
        const int Cs = kh * PWw + kw;
        bf16x8 af[4];
#pragma unroll
        for (int m = 0; m < 4; ++m) {
          int lin = ub0 + (m * 2304 + Cs * 128 + kc * 64);
          int msk = ((rm70 + (m * 2 + Cs)) & 7) << 4;
          af[m] = *(const bf16x8*)(ldsb + (lin ^ msk));
        }
        __builtin_amdgcn_s_setprio(1);
#pragma unroll
        for (int m = 0; m < 4; ++m)
#pragma unroll
          for (int n = 0; n < 4; ++n)
            acc[m][n] = __builtin_amdgcn_mfma_f32_16x16x32_bf16(af[m], Hf[n], acc[m][n], 0, 0, 0);
        __builtin_amdgcn_s_setprio(0);
        if (s < 17) loadBh(ch * 18 + s + 1);  // WAR on Hf: safe, MFMAs issued
      }
    }
  }

  // ---- epilogue: C/D map col=lane&15 (cout), row=(lane>>4)*4+reg (pw) ----
  float* ob = out + (size_t)b * HO * WO * CO;
#pragma unroll
  for (int m = 0; m < 4; ++m) {
    int hp = h0 + wr * 4 + m;
    if (hp >= HO) continue;
#pragma unroll
    for (int r = 0; r < 4; ++r) {
      int wp = w0 + ks * 4 + r;
      if (wp >= WO) continue;
#pragma unroll
      for (int n = 0; n < 4; ++n) {
        int co = wc * 64 + n * 16 + lr;
        ob[((size_t)hp * WO + wp) * CO + co] = acc[m][n][r];
      }
    }
  }
}

extern "C" void kernel_launch(void* const* d_in, const int* in_sizes, int n_in,
                              void* d_out, int out_size, void* d_ws, size_t ws_size,
                              hipStream_t stream) {
  const float* X = (const float*)d_in[0];
  const float* Kf = (const float*)d_in[1];
  float* out = (float*)d_out;
  size_t need = (size_t)NB * 9 * CI * CO * sizeof(unsigned short);  // 9.4 MB
  if (d_ws != nullptr && ws_size >= need) {
    unsigned short* ktr = (unsigned short*)d_ws;
    prep_kt<<<dim3(NB * 9), 256, 0, stream>>>(Kf, ktr);
    conv_main<<<dim3(2048), 512, 0, stream>>>(X, ktr, out);
  } else {
    int total = NB * HO * WO * CO;
    conv_naive<<<(total + 255) / 256, 256, 0, stream>>>(X, Kf, out);
  }
}

// Round 4
// 204.312 us; speedup vs baseline: 1.2537x; 1.2537x over previous
//
#include <hip/hip_runtime.h>
#include <stdint.h>

typedef __attribute__((ext_vector_type(8))) short bf16x8;
typedef __attribute__((ext_vector_type(4))) float f32x4;
typedef __attribute__((ext_vector_type(4))) unsigned short u16x4;

#define NB 32
#define HH 128
#define WW 128
#define CI 128
#define CO 128
#define HO 126
#define WO 126
#define TH 16
#define TW 16
#define PHh 18
#define PWw 18
#define NROW (PHh * PWw)   // 324 patch rows
#define RSTR 72            // shorts per LDS row (144 B): affine, 2-way max on reads
#define RSTRB 144

__device__ __forceinline__ unsigned short f2bf(float f) {
  union { float f; unsigned u; } x; x.f = f;
  unsigned u = x.u;
  u += 0x7FFFu + ((u >> 16) & 1u);   // RNE round to bf16
  return (unsigned short)(u >> 16);
}

// cvt_pk_bf16_f32: RNE, packs 2 f32 -> 2 bf16 in one VALU op (no builtin on gfx950)
__device__ __forceinline__ unsigned cvtpk_bf16(float a, float b) {
  unsigned r;
  asm("v_cvt_pk_bf16_f32 %0, %1, %2" : "=v"(r) : "v"(a), "v"(b));
  return r;  // low16 = bf16(a), high16 = bf16(b)
}

// prep: [b,p][ci][co] f32 -> fragment-blocked bf16, slice-major [b][ch][p][kc]:
//   slice = (ch*9+p)*2+kc (4096 shorts each); within: f*512 + lane*8 + e
//   holds kin[b,p][ci = ch*64+kc*32+(lane>>4)*8+e][co = (f>>2)*64+(f&3)*16+(lane&15)]
__global__ void prep_kt(const float* __restrict__ kin, unsigned short* __restrict__ ktr) {
  __shared__ unsigned short t[CI * CO];  // 32 KB
  int bp = blockIdx.x;  // b*9+p, 0..287
  int b = bp / 9, p = bp % 9;
  const float* src = kin + (size_t)bp * (CI * CO);
  unsigned short* dstb = ktr + (size_t)b * (9 * CI * CO);
  for (int i = threadIdx.x; i < CI * CO / 4; i += blockDim.x) {
    f32x4 v = *(const f32x4*)(src + i * 4);
    u16x4 o;
    o.x = f2bf(v.x); o.y = f2bf(v.y); o.z = f2bf(v.z); o.w = f2bf(v.w);
    *(u16x4*)&t[i * 4] = o;
  }
  __syncthreads();
  for (int j = threadIdx.x; j < 2048; j += blockDim.x) {  // j = (sl*8+f)*64+lane
    int lane = j & 63, f = (j >> 6) & 7, sl = j >> 9;     // sl = ch*2+kc
    int ch = sl >> 1, kc = sl & 1;
    int co = (f >> 2) * 64 + (f & 3) * 16 + (lane & 15);
    int ci0 = ch * 64 + kc * 32 + (lane >> 4) * 8;
    bf16x8 v;
#pragma unroll
    for (int e = 0; e < 8; ++e) v[e] = t[(ci0 + e) * CO + co];
    int slice = (ch * 9 + p) * 2 + kc;
    *(bf16x8*)&dstb[(size_t)slice * 4096 + f * 512 + lane * 8] = v;
  }
}

// naive fallback (only if ws_size too small — not expected on this harness)
__global__ void conv_naive(const float* __restrict__ X, const float* __restrict__ Kf,
                           float* __restrict__ out) {
  int idx = blockIdx.x * blockDim.x + threadIdx.x;           // over B*HO*WO*CO
  if (idx >= NB * HO * WO * CO) return;
  int co = idx & 127, t = idx >> 7;
  int wp = t % WO; t /= WO;
  int hp = t % HO; int b = t / HO;
  const float* xb = X + (size_t)b * HH * WW * CI;
  const float* kb = Kf + (size_t)b * 9 * CI * CO;
  float s = 0.f;
  for (int p = 0; p < 9; ++p) {
    int kh = p / 3, kw = p % 3;
    const float* xr = xb + ((size_t)(hp + kh) * WW + (wp + kw)) * CI;
    const float* kr = kb + (size_t)p * CI * CO + co;
    for (int ci = 0; ci < CI; ++ci) s += xr[ci] * kr[(size_t)ci * CO];
  }
  out[idx] = s;
}

__global__ __launch_bounds__(512, 4) void conv_main(
    const float* __restrict__ X, const unsigned short* __restrict__ Kt,
    float* __restrict__ out) {
  // One Cin-half of the 18x18 input patch; rows padded to 144 B so every
  // compute-loop LDS address is base + compile-time immediate (nothing for
  // the compiler to hoist -> no spill; R3's spill source was 144 hoisted
  // swizzled addresses). Bank math: read stride 36 dwords -> lanes (lr,lr+8)
  // pair on a 4-bank group = 2-way = free (m136); writes hit 32 banks 1-way.
  __shared__ unsigned short lds_a[NROW * RSTR];  // 46656 B -> 2 blocks/CU

  const int tid = threadIdx.x;
  const int lane = tid & 63;
  const int wid = tid >> 6;            // 8 waves, 4 (h) x 2 (co)
  const int wr = wid >> 1, wc = wid & 1;

  // XCD-clustered block swizzle: 4 whole batches per XCD keeps the B working
  // set L2-resident (verified: FETCH 200->146MB).
  const int l = blockIdx.x;            // 0..2047
  const int xcd = l & 7, j = l >> 3;   // j: 0..255
  const int b = xcd * 4 + (j >> 6);    // 4 batches per XCD
  const int t = j & 63;                // tile within batch (8x8 of 16x16)
  const int ht = t >> 3, wt = t & 7;
  const int h0 = ht * TH, w0 = wt * TW;
  const int ks = lane >> 4, lr = lane & 15;

  const float* xb = X + (size_t)b * HH * WW * CI;

  // ---- stage precompute: slot s = tid + k*512; row = (tid>>4) + 32k ----
  // affine layout: dst byte = row*144 + ci4*8, advances exactly 4608 B per k.
  const int ci4 = tid & 15;
  const int row0 = tid >> 4;                  // 0..31
  const int hi0 = (row0 >= PWw) ? 1 : 0;
  const int wi0 = row0 - hi0 * PWw;
  char* const dst0 = (char*)lds_a + row0 * RSTRB + ci4 * 8;

  auto stageA = [&](int ch) {
    int h = hi0, w = wi0;
    const float* srcb = xb + ch * 64 + ci4 * 4;
#pragma unroll
    for (int k = 0; k < 11; ++k) {            // 10 full rounds + 4-row tail
      if (k < 10 || tid < 64) {
        int gh = h0 + h, gw = w0 + w;
        bool ok = (gh | gw) < HH;             // gh<128 && gw<128 (both <256)
        const float* src = srcb + ((size_t)(((gh & 127) << 7) + (gw & 127)) << 7);
        f32x4 v = *(const f32x4*)src;
        uint2 o;
        o.x = ok ? cvtpk_bf16(v.x, v.y) : 0u;
        o.y = ok ? cvtpk_bf16(v.z, v.w) : 0u;
        *(uint2*)(dst0 + k * (32 * RSTRB)) = o;  // offset folds into ds imm
      }
      w += 14;                                // advance 32 rows: h+=1, w+=14 wrap
      int wrap = (w >= PWw) ? 1 : 0;
      h += 1 + wrap;
      w -= wrap ? PWw : 0;
    }
  };

  // ---- compute: af byte addr = aoff + (m+kh)*18*144 + kw*144 + kc*64 ----
  // all-immediate offsets off one per-thread base register (max 46.6 KB,
  // fits the 16-bit ds offset).
  const int aoff = ((wr * 4) * PWw + lr) * RSTRB + ks * 16;
  const char* ldsb = (const char*)lds_a;

  f32x4 zero = {0.f, 0.f, 0.f, 0.f};
  f32x4 acc[4][4];
#pragma unroll
  for (int m = 0; m < 4; ++m)
#pragma unroll
    for (int n = 0; n < 4; ++n) acc[m][n] = zero;

  // B slices: slice = (ch*9+p)*2+kc; wave loads its 4 co-fragments as 4
  // contiguous 1KB bursts (L2/L1-resident after XCD clustering).
  const unsigned short* ktw = Kt + (size_t)b * 9 * CI * CO + (wc * 4) * 512 + lane * 8;

  bf16x8 Hf[4];
  auto loadBh = [&](int slice) {
#pragma unroll
    for (int n = 0; n < 4; ++n)
      Hf[n] = *(const bf16x8*)&ktw[(size_t)slice * 4096 + n * 512];
  };

#pragma unroll 1
  for (int ch = 0; ch < 2; ++ch) {
    if (ch) __syncthreads();           // all waves done reading previous half
    loadBh(ch * 18);                   // B prefetch flies during staging
    stageA(ch);
    __syncthreads();                   // lds_a ready

    // fully-unrolled 18 half-steps: all offsets compile-time immediates
#pragma unroll
    for (int kh = 0; kh < 3; ++kh) {
#pragma unroll
      for (int jj = 0; jj < 6; ++jj) {
        const int kw = jj >> 1, kc = jj & 1;
        const int s = kh * 6 + jj;
        bf16x8 af[4];
#pragma unroll
        for (int m = 0; m < 4; ++m)
          af[m] = *(const bf16x8*)(ldsb + aoff +
                                   ((m + kh) * PWw * RSTRB + kw * RSTRB + kc * 64));
        __builtin_amdgcn_s_setprio(1);
#pragma unroll
        for (int m = 0; m < 4; ++m)
#pragma unroll
          for (int n = 0; n < 4; ++n)
            acc[m][n] = __builtin_amdgcn_mfma_f32_16x16x32_bf16(af[m], Hf[n], acc[m][n], 0, 0, 0);
        __builtin_amdgcn_s_setprio(0);
        if (s < 17) loadBh(ch * 18 + s + 1);  // WAR on Hf: safe, MFMAs issued
      }
    }
  }

  // ---- epilogue: C/D map col=lane&15 (cout), row=(lane>>4)*4+reg (pw) ----
  float* ob = out + (size_t)b * HO * WO * CO;
#pragma unroll
  for (int m = 0; m < 4; ++m) {
    int hp = h0 + wr * 4 + m;
    if (hp >= HO) continue;
#pragma unroll
    for (int r = 0; r < 4; ++r) {
      int wp = w0 + ks * 4 + r;
      if (wp >= WO) continue;
#pragma unroll
      for (int n = 0; n < 4; ++n) {
        int co = wc * 64 + n * 16 + lr;
        ob[((size_t)hp * WO + wp) * CO + co] = acc[m][n][r];
      }
    }
  }
}

extern "C" void kernel_launch(void* const* d_in, const int* in_sizes, int n_in,
                              void* d_out, int out_size, void* d_ws, size_t ws_size,
                              hipStream_t stream) {
  const float* X = (const float*)d_in[0];
  const float* Kf = (const float*)d_in[1];
  float* out = (float*)d_out;
  size_t need = (size_t)NB * 9 * CI * CO * sizeof(unsigned short);  // 9.4 MB
  if (d_ws != nullptr && ws_size >= need) {
    unsigned short* ktr = (unsigned short*)d_ws;
    prep_kt<<<dim3(NB * 9), 256, 0, stream>>>(Kf, ktr);
    conv_main<<<dim3(2048), 512, 0, stream>>>(X, ktr, out);
  } else {
    int total = NB * HO * WO * CO;
    conv_naive<<<(total + 255) / 256, 256, 0, stream>>>(X, Kf, out);
  }
}